// Round 1
// baseline (584.160 us; speedup 1.0000x reference)
//
#include <hip/hip_runtime.h>

// Masked inclusive cumsum along rows: out[r, :] = cumsum(where(mask, x, 0), axis=1)
// ROWS=2048, N=32768 = 8 tiles * 1024 threads * 4 (float4 per thread per tile).
//
// One block per row. Per tile:
//   1. float4 load x, int4 load mask (harness passes bool as int32)
//   2. per-thread masked sum of 4, wave-64 shuffle inclusive scan
//   3. cross-wave exclusive offset via 16-entry LDS wave-total array
//   4. row carry kept in a register identically replicated across all threads
//      (every thread sums all 16 wave totals) -> only 2 syncthreads per tile
//   5. prefetch tile t+1 before computing tile t to hide HBM latency

#define ROWS    2048
#define NCOL    32768
#define THREADS 1024
#define TILES   8   // NCOL / (THREADS * 4)

__global__ __launch_bounds__(THREADS, 2) void masked_cumsum_kernel(
    const float* __restrict__ x,
    const int*   __restrict__ mask,
    float*       __restrict__ out)
{
    const int row = blockIdx.x;
    const size_t base = (size_t)row * NCOL;
    const float4* __restrict__ xrow = (const float4*)(x + base);
    const int4*   __restrict__ mrow = (const int4*)(mask + base);
    float4*       __restrict__ orow = (float4*)(out + base);

    const int tid  = threadIdx.x;
    const int lane = tid & 63;
    const int wave = tid >> 6;

    __shared__ float wsum[16];

    float carry = 0.0f;  // same value in every thread of the block

    // Prefetch tile 0
    float4 xv = xrow[tid];
    int4   mv = mrow[tid];

    #pragma unroll
    for (int t = 0; t < TILES; ++t) {
        // Prefetch next tile while we compute this one
        float4 xn; int4 mn;
        if (t + 1 < TILES) {
            xn = xrow[(t + 1) * THREADS + tid];
            mn = mrow[(t + 1) * THREADS + tid];
        }

        // Masked values + per-thread inclusive prefix of 4
        float a0 = mv.x ? xv.x : 0.0f;
        float a1 = mv.y ? xv.y : 0.0f;
        float a2 = mv.z ? xv.z : 0.0f;
        float a3 = mv.w ? xv.w : 0.0f;
        float s0 = a0;
        float s1 = s0 + a1;
        float s2 = s1 + a2;
        float s3 = s2 + a3;

        // Wave-64 inclusive scan of thread sums
        float sc = s3;
        #pragma unroll
        for (int d = 1; d < 64; d <<= 1) {
            float o = __shfl_up(sc, d);
            if (lane >= d) sc += o;
        }

        // Publish wave totals
        if (lane == 63) wsum[wave] = sc;
        __syncthreads();

        // Every thread reads all 16 wave totals: exclusive offset for its own
        // wave + grand total (for the carry register, identical in all threads)
        float woff = 0.0f, total = 0.0f;
        #pragma unroll
        for (int w = 0; w < 16; ++w) {
            float ws = wsum[w];
            woff  += (w < wave) ? ws : 0.0f;
            total += ws;
        }

        float b = carry + woff + (sc - s3);  // exclusive prefix for this thread
        orow[t * THREADS + tid] = make_float4(b + s0, b + s1, b + s2, b + s3);

        carry += total;
        xv = xn; mv = mn;
        __syncthreads();  // protect wsum before next tile overwrites it
    }
}

extern "C" void kernel_launch(void* const* d_in, const int* in_sizes, int n_in,
                              void* d_out, int out_size, void* d_ws, size_t ws_size,
                              hipStream_t stream) {
    const float* x    = (const float*)d_in[0];
    const int*   mask = (const int*)d_in[1];
    float*       out  = (float*)d_out;
    masked_cumsum_kernel<<<ROWS, THREADS, 0, stream>>>(x, mask, out);
}

// Round 2
// 570.166 us; speedup vs baseline: 1.0245x; 1.0245x over previous
//
#include <hip/hip_runtime.h>

// Masked inclusive cumsum along rows: out[r, :] = cumsum(where(mask, x, 0), axis=1)
// ROWS=2048, N=32768. One 1024-thread block per row, whole row in registers.
//
// R1 was latency-bound (2.7 TB/s, VALUBusy 17%): 8 serial tiles x 2 wide
// barriers each. R2: load ALL 8 tiles up-front (16 independent global loads,
// full MLP), one single block-scan over the 8192 float4-chunk sums:
//   Phase A: load x(float4) + mask(int4) for all tiles; per-chunk inclusive
//            prefix in registers; chunk sum -> padded LDS array.
//   Phase B: thread j serially scans chunk sums 8j..8j+7 (LDS read, 2-way
//            conflict = free), wave-64 shuffle scan of thread totals,
//            cross-wave via 16-entry LDS, write exclusive chunk offsets back.
//   Phase C: each thread adds its chunks' offsets and stores float4s.
// 3 barriers per row (was 16). LDS pad: index c -> c + (c>>3).

#define ROWS    2048
#define NCOL    32768
#define THREADS 1024
#define TILES   8                    // NCOL / (THREADS*4)
#define NCHUNK  (THREADS * TILES)    // 8192 float4-chunks per row

__global__ __launch_bounds__(THREADS, 1) void masked_cumsum_kernel(
    const float* __restrict__ x,
    const int*   __restrict__ mask,
    float*       __restrict__ out)
{
    const int row = blockIdx.x;
    const size_t base = (size_t)row * NCOL;
    const float4* __restrict__ xrow = (const float4*)(x + base);
    const int4*   __restrict__ mrow = (const int4*)(mask + base);
    float4*       __restrict__ orow = (float4*)(out + base);

    const int tid  = threadIdx.x;
    const int lane = tid & 63;
    const int wave = tid >> 6;

    // Padded chunk-sum array: chunk c lives at c + (c>>3).  8192+1024 floats.
    __shared__ float csum[NCHUNK + NCHUNK / 8];
    __shared__ float wtot[16];

    // ---- Phase A: load everything (16 independent loads), mask, chunk prefix
    float4 xv[TILES];
    int4   mv[TILES];
    #pragma unroll
    for (int t = 0; t < TILES; ++t) {
        xv[t] = xrow[t * THREADS + tid];
        mv[t] = mrow[t * THREADS + tid];
    }

    float4 p[TILES];  // per-chunk inclusive prefixes (overwrites values)
    #pragma unroll
    for (int t = 0; t < TILES; ++t) {
        float a0 = mv[t].x ? xv[t].x : 0.0f;
        float a1 = mv[t].y ? xv[t].y : 0.0f;
        float a2 = mv[t].z ? xv[t].z : 0.0f;
        float a3 = mv[t].w ? xv[t].w : 0.0f;
        p[t].x = a0;
        p[t].y = p[t].x + a1;
        p[t].z = p[t].y + a2;
        p[t].w = p[t].z + a3;
        int c = t * THREADS + tid;
        csum[c + (c >> 3)] = p[t].w;
    }
    __syncthreads();

    // ---- Phase B: block scan over 8192 chunk sums.
    // Thread j owns chunks 8j..8j+7 -> padded LDS indices 9j..9j+7 (2-way, free)
    float s[8];
    float run = 0.0f;
    #pragma unroll
    for (int k = 0; k < 8; ++k) {
        run += csum[tid * 9 + k];
        s[k] = run;                 // inclusive prefix of this thread's 8 sums
    }

    // Wave-64 inclusive scan of thread totals
    float sc = run;
    #pragma unroll
    for (int d = 1; d < 64; d <<= 1) {
        float o = __shfl_up(sc, d);
        if (lane >= d) sc += o;
    }
    if (lane == 63) wtot[wave] = sc;
    __syncthreads();

    float woff = 0.0f;
    #pragma unroll
    for (int w = 0; w < 16; ++w)
        woff += (w < wave) ? wtot[w] : 0.0f;

    const float thr_excl = woff + (sc - run);  // exclusive prefix of chunk 8j

    // Write exclusive chunk offsets back to the same (private) LDS slots.
    #pragma unroll
    for (int k = 0; k < 8; ++k)
        csum[tid * 9 + k] = thr_excl + (k ? s[k - 1] : 0.0f);
    __syncthreads();

    // ---- Phase C: add offsets, store
    #pragma unroll
    for (int t = 0; t < TILES; ++t) {
        int c = t * THREADS + tid;
        float off = csum[c + (c >> 3)];
        orow[t * THREADS + tid] =
            make_float4(off + p[t].x, off + p[t].y, off + p[t].z, off + p[t].w);
    }
}

extern "C" void kernel_launch(void* const* d_in, const int* in_sizes, int n_in,
                              void* d_out, int out_size, void* d_ws, size_t ws_size,
                              hipStream_t stream) {
    const float* x    = (const float*)d_in[0];
    const int*   mask = (const int*)d_in[1];
    float*       out  = (float*)d_out;
    masked_cumsum_kernel<<<ROWS, THREADS, 0, stream>>>(x, mask, out);
}